// Round 4
// baseline (14998.299 us; speedup 1.0000x reference)
//
#include <hip/hip_runtime.h>
#include <math.h>

#define HID 100
#define TOK 200
#define HALF 50

// ---------------------------------------------------------------------------
// Edge kernel: per edge e: te = cos(rel_t*w+b) ; tokens=[te,msg] ;
// h = LN(tokens@feat_W + feat_b) ; h += gelu(h@tf0)@tf1 ; atomic scatter to dst.
// 512 threads = 8 waves; each wave processes 4 edges per iteration.
// All weights live in LDS (staged once per block). ~148 KB LDS -> 1 block/CU.
// ---------------------------------------------------------------------------
__global__ __launch_bounds__(512)
void edge_kernel(const float* __restrict__ lu, const int* __restrict__ ei,
                 const float* __restrict__ tt, const float* __restrict__ msg,
                 const float* __restrict__ time_w, const float* __restrict__ time_b,
                 const float* __restrict__ feat_W, const float* __restrict__ feat_b,
                 const float* __restrict__ tln_g, const float* __restrict__ tln_b,
                 const float* __restrict__ tf0_W, const float* __restrict__ tf0_b,
                 const float* __restrict__ tf1_W, const float* __restrict__ tf1_b,
                 float* __restrict__ h_sum, float* __restrict__ cnt, int E)
{
    __shared__ __align__(16) float sW [TOK * HID];   // feat_W [k][c]
    __shared__ __align__(16) float sW0[HID * HALF];  // tf0_W  [c][j]
    __shared__ __align__(16) float sW1[HALF * HID];  // tf1_W  [j][c]
    __shared__ float sfb[HID], s0b[HALF], s1b[HID], sg[HID], sbv[HID], stw[HID], stb[HID];
    __shared__ __align__(16) float stok[8][4][TOK];  // per-wave tokens / hn / u

    const int tid = threadIdx.x;
    for (int i = tid; i < TOK * HID; i += 512) sW [i] = feat_W[i];
    for (int i = tid; i < HID * HALF; i += 512) sW0[i] = tf0_W[i];
    for (int i = tid; i < HALF * HID; i += 512) sW1[i] = tf1_W[i];
    if (tid < HID) { sfb[tid] = feat_b[tid]; s1b[tid] = tf1_b[tid]; sg[tid] = tln_g[tid];
                     sbv[tid] = tln_b[tid];  stw[tid] = time_w[tid]; stb[tid] = time_b[tid]; }
    if (tid < HALF) s0b[tid] = tf0_b[tid];
    __syncthreads();

    const int w    = tid >> 6;
    const int lane = tid & 63;
    const bool act1 = lane < (HID - 64);            // second channel lane+64 < 100
    const int  c0 = lane;
    const int  c1 = act1 ? lane + 64 : 0;
    const bool actj = lane < HALF;
    const int  jc  = actj ? lane : 0;
    const int  nG  = (E + 31) >> 5;                 // 32 edges per block-iteration

    for (int g = blockIdx.x; g < nG; g += gridDim.x) {
        const int ebase = g * 32 + w * 4;
        int dsts[4]; bool eok[4];

        // ---- phase A: build tokens [te | msg] for this wave's 4 edges ----
        #pragma unroll
        for (int e = 0; e < 4; ++e) {
            const int eidx = ebase + e;
            const bool ok  = eidx < E;
            const int  ec  = ok ? eidx : 0;
            eok[e] = ok;
            const int srcn = ei[ec];
            dsts[e] = ei[(size_t)E + ec];
            const float relt = lu[srcn] - tt[ec];
            for (int k = lane; k < TOK; k += 64) {
                float v;
                if (k < HID) v = cosf(fmaf(relt, stw[k], stb[k]));
                else         v = msg[(size_t)ec * HID + (k - HID)];
                stok[w][e][k] = v;
            }
        }
        __syncthreads();

        // ---- phase B: h = tokens @ feat_W + feat_b (lane owns c0 and maybe c1) ----
        float a0[4], a1[4];
        #pragma unroll
        for (int e = 0; e < 4; ++e) { a0[e] = sfb[c0]; a1[e] = sfb[c1]; }
        for (int k = 0; k < TOK; k += 4) {
            float4 tv[4];
            #pragma unroll
            for (int e = 0; e < 4; ++e) tv[e] = *(const float4*)&stok[w][e][k];
            #pragma unroll
            for (int kk = 0; kk < 4; ++kk) {
                const float wa = sW[(k + kk) * HID + c0];
                const float wb = sW[(k + kk) * HID + c1];
                #pragma unroll
                for (int e = 0; e < 4; ++e) {
                    const float tk = ((const float*)&tv[e])[kk];
                    a0[e] = fmaf(tk, wa, a0[e]);
                    a1[e] = fmaf(tk, wb, a1[e]);
                }
            }
        }

        // ---- phase C: LayerNorm across 100 channels (wave butterfly) ----
        float hn0[4], hn1[4];
        #pragma unroll
        for (int e = 0; e < 4; ++e) {
            float s  = a0[e]       + (act1 ? a1[e]        : 0.0f);
            float qq = a0[e]*a0[e] + (act1 ? a1[e]*a1[e]  : 0.0f);
            #pragma unroll
            for (int off = 32; off >= 1; off >>= 1) {
                s  += __shfl_xor(s,  off);
                qq += __shfl_xor(qq, off);
            }
            const float mu = s * 0.01f;
            const float rs = rsqrtf(qq * 0.01f - mu * mu + 1e-5f);
            hn0[e] = (a0[e] - mu) * rs * sg[c0] + sbv[c0];
            hn1[e] = (a1[e] - mu) * rs * sg[c1] + sbv[c1];
            stok[w][e][c0] = hn0[e];
            if (act1) stok[w][e][c1] = hn1[e];
        }
        __syncthreads();

        // ---- phase D: u = gelu(hn @ tf0_W + tf0_b)  (lanes 0..49 own j) ----
        float u[4];
        #pragma unroll
        for (int e = 0; e < 4; ++e) u[e] = s0b[jc];
        for (int c = 0; c < HID; c += 4) {
            float4 hv4[4];
            #pragma unroll
            for (int e = 0; e < 4; ++e) hv4[e] = *(const float4*)&stok[w][e][c];
            #pragma unroll
            for (int cc = 0; cc < 4; ++cc) {
                const float wv = sW0[(c + cc) * HALF + jc];
                #pragma unroll
                for (int e = 0; e < 4; ++e)
                    u[e] = fmaf(((const float*)&hv4[e])[cc], wv, u[e]);
            }
        }
        #pragma unroll
        for (int e = 0; e < 4; ++e) {
            const float xx  = u[e];
            const float gel = 0.5f * xx * (1.0f + erff(xx * 0.70710678118654752f));
            if (actj) stok[w][e][HID + jc] = gel;
        }
        __syncthreads();

        // ---- phase E: h_tok = u @ tf1_W + tf1_b ; final = hn + h_tok ----
        float b0[4], b1[4];
        #pragma unroll
        for (int e = 0; e < 4; ++e) { b0[e] = s1b[c0]; b1[e] = s1b[c1]; }
        for (int j = 0; j < HALF; j += 2) {
            float2 uv[4];
            #pragma unroll
            for (int e = 0; e < 4; ++e) uv[e] = *(const float2*)&stok[w][e][HID + j];
            #pragma unroll
            for (int jj = 0; jj < 2; ++jj) {
                const float wa = sW1[(j + jj) * HID + c0];
                const float wb = sW1[(j + jj) * HID + c1];
                #pragma unroll
                for (int e = 0; e < 4; ++e) {
                    const float uu = ((const float*)&uv[e])[jj];
                    b0[e] = fmaf(uu, wa, b0[e]);
                    b1[e] = fmaf(uu, wb, b1[e]);
                }
            }
        }

        // ---- phase F: atomic scatter-add to h_sum[dst], cnt[dst] ----
        #pragma unroll
        for (int e = 0; e < 4; ++e) {
            if (!eok[e]) continue;
            float* base = h_sum + (size_t)dsts[e] * HID;
            atomicAdd(base + c0, hn0[e] + b0[e]);
            if (act1) atomicAdd(base + c1, hn1[e] + b1[e]);
            if (lane == 0) atomicAdd(&cnt[dsts[e]], 1.0f);
        }
        __syncthreads();
    }
}

// ---------------------------------------------------------------------------
// Node kernel: h_node = h_sum/max(cnt,1);
// h_node += gelu(LN(h_node)@cf0)@cf1 ; out = LN(h_node@proj+b) + x@res_W + res_b.
// 64 nodes/block, 256 threads (4 threads per node, 25 channels each).
// Weight tiles staged 100x100 at a time in LDS.
// ---------------------------------------------------------------------------
__global__ __launch_bounds__(256)
void node_kernel(const float* __restrict__ h_sum, const float* __restrict__ cnt,
                 const float* __restrict__ x,
                 const float* __restrict__ cln_g, const float* __restrict__ cln_b,
                 const float* __restrict__ cf0_W, const float* __restrict__ cf0_b,
                 const float* __restrict__ cf1_W, const float* __restrict__ cf1_b,
                 const float* __restrict__ proj_W, const float* __restrict__ proj_b,
                 const float* __restrict__ res_W, const float* __restrict__ res_b,
                 const float* __restrict__ oln_g, const float* __restrict__ oln_b,
                 float* __restrict__ out, int N)
{
    __shared__ __align__(16) float sA[64 * HID];    // hcs / h2
    __shared__ __align__(16) float sB[HID * HID];   // weight tile
    __shared__ __align__(16) float sC[64 * HID];    // h_node raw / hc4 / x tile

    const int tid = threadIdx.x;
    const int nl  = tid >> 2;        // 0..63 node-in-block
    const int q   = tid & 3;         // channel quarter
    const int blockBase = blockIdx.x * 64;
    const int node = blockBase + nl;
    const bool nok = node < N;

    // h_node = h_sum / max(cnt,1)  (coalesced into sC)
    for (int i = tid; i < 64 * HID; i += 256) {
        const int ng = blockBase + i / HID;
        float v = 0.0f;
        if (ng < N) {
            const float c = cnt[ng];
            v = h_sum[(size_t)blockBase * HID + i] / fmaxf(c, 1.0f);
        }
        sC[i] = v;
    }
    __syncthreads();

    // LN(h_node) -> sA ; keep raw h_node in regs (hv)
    float hv[25];
    float s = 0.0f, ss = 0.0f;
    #pragma unroll
    for (int i = 0; i < 25; ++i) {
        const float v = sC[nl * HID + q * 25 + i];
        hv[i] = v; s += v; ss += v * v;
    }
    s  += __shfl_xor(s, 1);  s  += __shfl_xor(s, 2);
    ss += __shfl_xor(ss, 1); ss += __shfl_xor(ss, 2);
    {
        const float mu = s * 0.01f;
        const float rs = rsqrtf(ss * 0.01f - mu * mu + 1e-5f);
        #pragma unroll
        for (int i = 0; i < 25; ++i) {
            const int c = q * 25 + i;
            sA[nl * HID + c] = (hv[i] - mu) * rs * cln_g[c] + cln_b[c];
        }
    }
    __syncthreads();

    // channel FFN: facc = gelu(sA @ cf0) @ cf1 + cf1_b   (4 tiles of 100)
    float facc[25];
    #pragma unroll
    for (int i = 0; i < 25; ++i) facc[i] = cf1_b[q * 25 + i];

    for (int jt = 0; jt < 4; ++jt) {
        for (int i = tid; i < HID * HID; i += 256) {
            const int r = i / HID, cc = i - r * HID;
            sB[i] = cf0_W[r * 400 + jt * HID + cc];
        }
        __syncthreads();

        float acc[25];
        #pragma unroll
        for (int jj = 0; jj < 25; ++jj) acc[jj] = cf0_b[jt * HID + q * 25 + jj];
        for (int c = 0; c < HID; ++c) {
            const float hb = sA[nl * HID + c];
            const float* wr = &sB[c * HID + q * 25];
            #pragma unroll
            for (int jj = 0; jj < 25; ++jj) acc[jj] = fmaf(hb, wr[jj], acc[jj]);
        }
        __syncthreads();
        #pragma unroll
        for (int jj = 0; jj < 25; ++jj) {
            const float xx = acc[jj];
            sC[nl * HID + q * 25 + jj] = 0.5f * xx * (1.0f + erff(xx * 0.70710678118654752f));
        }
        __syncthreads();

        for (int i = tid; i < HID * HID; i += 256)
            sB[i] = cf1_W[jt * HID * HID + i];
        __syncthreads();

        for (int j = 0; j < HID; ++j) {
            const float hb = sC[nl * HID + j];
            const float* wr = &sB[j * HID + q * 25];
            #pragma unroll
            for (int i = 0; i < 25; ++i) facc[i] = fmaf(hb, wr[i], facc[i]);
        }
        __syncthreads();
    }

    // h2 = h_node + ffn ; out1 = h2 @ proj + proj_b
    float h2[25];
    #pragma unroll
    for (int i = 0; i < 25; ++i) {
        h2[i] = hv[i] + facc[i];
        sA[nl * HID + q * 25 + i] = h2[i];
    }
    for (int i = tid; i < HID * HID; i += 256) sB[i] = proj_W[i];
    __syncthreads();

    float o1[25];
    #pragma unroll
    for (int i = 0; i < 25; ++i) o1[i] = proj_b[q * 25 + i];
    for (int k = 0; k < HID; ++k) {
        const float hb = sA[nl * HID + k];
        const float* wr = &sB[k * HID + q * 25];
        #pragma unroll
        for (int i = 0; i < 25; ++i) o1[i] = fmaf(hb, wr[i], o1[i]);
    }

    // LN(out1)
    float s2 = 0.0f, q2 = 0.0f;
    #pragma unroll
    for (int i = 0; i < 25; ++i) { s2 += o1[i]; q2 += o1[i] * o1[i]; }
    s2 += __shfl_xor(s2, 1); s2 += __shfl_xor(s2, 2);
    q2 += __shfl_xor(q2, 1); q2 += __shfl_xor(q2, 2);
    float on[25];
    {
        const float mu = s2 * 0.01f;
        const float rs = rsqrtf(q2 * 0.01f - mu * mu + 1e-5f);
        #pragma unroll
        for (int i = 0; i < 25; ++i) {
            const int c = q * 25 + i;
            on[i] = (o1[i] - mu) * rs * oln_g[c] + oln_b[c];
        }
    }
    __syncthreads();

    // residual: x @ res_W + res_b
    for (int i = tid; i < HID * HID; i += 256) sB[i] = res_W[i];
    for (int i = tid; i < 64 * HID; i += 256) {
        const int ng = blockBase + i / HID;
        sC[i] = (ng < N) ? x[(size_t)blockBase * HID + i] : 0.0f;
    }
    __syncthreads();

    float ro[25];
    #pragma unroll
    for (int i = 0; i < 25; ++i) ro[i] = res_b[q * 25 + i];
    for (int k = 0; k < HID; ++k) {
        const float xb = sC[nl * HID + k];
        const float* wr = &sB[k * HID + q * 25];
        #pragma unroll
        for (int i = 0; i < 25; ++i) ro[i] = fmaf(xb, wr[i], ro[i]);
    }

    if (nok) {
        #pragma unroll
        for (int i = 0; i < 25; ++i)
            out[(size_t)node * HID + q * 25 + i] = on[i] + ro[i];
    }
}

// ---------------------------------------------------------------------------
extern "C" void kernel_launch(void* const* d_in, const int* in_sizes, int n_in,
                              void* d_out, int out_size, void* d_ws, size_t ws_size,
                              hipStream_t stream)
{
    const float* x      = (const float*)d_in[0];
    const float* lu     = (const float*)d_in[1];
    const int*   ei     = (const int*)d_in[2];     // harness delivers integer inputs as int32
    const float* tt     = (const float*)d_in[3];
    const float* msg    = (const float*)d_in[4];
    const float* time_w = (const float*)d_in[5];
    const float* time_b = (const float*)d_in[6];
    const float* feat_W = (const float*)d_in[7];
    const float* feat_b = (const float*)d_in[8];
    const float* tln_g  = (const float*)d_in[9];
    const float* tln_b  = (const float*)d_in[10];
    const float* tf0_W  = (const float*)d_in[11];
    const float* tf0_b  = (const float*)d_in[12];
    const float* tf1_W  = (const float*)d_in[13];
    const float* tf1_b  = (const float*)d_in[14];
    const float* cln_g  = (const float*)d_in[15];
    const float* cln_b  = (const float*)d_in[16];
    const float* cf0_W  = (const float*)d_in[17];
    const float* cf0_b  = (const float*)d_in[18];
    const float* cf1_W  = (const float*)d_in[19];
    const float* cf1_b  = (const float*)d_in[20];
    const float* proj_W = (const float*)d_in[21];
    const float* proj_b = (const float*)d_in[22];
    const float* res_W  = (const float*)d_in[23];
    const float* res_b  = (const float*)d_in[24];
    const float* oln_g  = (const float*)d_in[25];
    const float* oln_b  = (const float*)d_in[26];

    const int N = in_sizes[1];    // last_update
    const int E = in_sizes[3];    // t

    float* h_sum = (float*)d_ws;                 // N*100 f32
    float* cnt   = h_sum + (size_t)N * HID;      // N f32
    hipMemsetAsync(d_ws, 0, ((size_t)N * HID + N) * sizeof(float), stream);

    const int nG = (E + 31) / 32;
    const int egrid = nG < 2048 ? nG : 2048;
    edge_kernel<<<egrid, 512, 0, stream>>>(lu, ei, tt, msg, time_w, time_b,
        feat_W, feat_b, tln_g, tln_b, tf0_W, tf0_b, tf1_W, tf1_b, h_sum, cnt, E);

    node_kernel<<<(N + 63) / 64, 256, 0, stream>>>(h_sum, cnt, x,
        cln_g, cln_b, cf0_W, cf0_b, cf1_W, cf1_b, proj_W, proj_b,
        res_W, res_b, oln_g, oln_b, (float*)d_out, N);
}